// Round 12
// baseline (4025.705 us; speedup 1.0000x reference)
//
#include <hip/hip_runtime.h>
#include <math.h>

#define Bz   256
#define Tz   512
#define Sz   8
#define CD1  5
#define Hz   520
#define H4   2080
#define Ez   1024
#define Dz   1040

// persistent LSTM geometry
#define NG   16     // row groups
#define NSL  16     // j-slices per group (NG*NSL = 256 WGs, 1 per CU)
#define RG   16     // rows per group
#define JW   34     // j per slice (16*34 = 544 >= 520)
#define NW   136    // gate columns per slice (JW*4)
#define KW   520    // K extent
#define KD   260    // packed dwords (= tagged qwords) per row
#define KIT  17     // k-iterations of 32 (ceil(520/32))
#define HGTQ 4160   // tagged qwords per group (RG*KD)
#define NTHR 512    // threads per WG (8 waves)

typedef float f32x4 __attribute__((ext_vector_type(4)));
typedef short s16x8 __attribute__((ext_vector_type(8)));
typedef unsigned long long ull;

__device__ __forceinline__ ushort f2bf(float f) {
    uint u = __float_as_uint(f);
    uint r = (u + 0x7fffu + ((u >> 16) & 1u)) >> 16;
    return (ushort)r;
}
__device__ __forceinline__ float bf2f(ushort h) { return __uint_as_float(((uint)h) << 16); }
__device__ __forceinline__ float sigf(float v) { return 1.0f / (1.0f + expf(-v)); }

// rank-sort rows by h_len descending (ties by index) — O(n^2), one block
__global__ void k_sort(const int* __restrict__ hl, int* __restrict__ sortedidx) {
    __shared__ int s[Bz];
    int i = threadIdx.x;
    s[i] = hl[i];
    __syncthreads();
    int mine = s[i], rank = 0;
    for (int j = 0; j < Bz; j++) {
        int o = s[j];
        rank += (o > mine) || (o == mine && j < i);
    }
    sortedidx[rank] = i;
}

// W_hh -> bf16, layout wbt[n][k], n_global = s*NW + nl; j = n_global>>2, gate = n&3
__global__ void k_prep_w(const float* __restrict__ whh, ushort* __restrict__ wbt) {
    int idx = blockIdx.x * 256 + threadIdx.x;
    if (idx >= NW * NSL * KW) return;
    int n = idx / KW, k = idx - n * KW;
    int j = n >> 2, gate = n & 3;
    float v = (j < Hz) ? whh[(size_t)k * H4 + gate * Hz + j] : 0.0f;
    wbt[idx] = f2bf(v);
}

// permute h0_stack rows into sorted order, TAGGED (tag=0xFFFF) qwords, into buffer 1
__global__ void k_hinit(const float* __restrict__ hA, const int* __restrict__ sortedidx,
                        ull* __restrict__ h_buf1) {
    int idx = blockIdx.x * 256 + threadIdx.x;
    if (idx >= Bz * KD) return;
    int rank = idx / KD, kd = idx - rank * KD;
    const float* src = hA + (size_t)sortedidx[rank] * KW + 2 * kd;
    uint lo = 0xFFFF0000u | (uint)f2bf(src[0]);
    uint hi = 0xFFFF0000u | (uint)f2bf(src[1]);
    h_buf1[idx] = (ull)lo | ((ull)hi << 32);
}

// out[m][n] = act( in[m][:] @ w[:][n] + bias[n] ), 4 rows/block, 256 threads over n
template<int K, int N, int ACT>
__global__ void k_mlp(const float* __restrict__ in, const float* __restrict__ w,
                      const float* __restrict__ bias, float* __restrict__ out) {
    int n  = blockIdx.x * 256 + threadIdx.x;
    int m0 = blockIdx.y * 4;
    if (n >= N) return;
    float acc[4];
    float bv = bias[n];
    #pragma unroll
    for (int i = 0; i < 4; i++) acc[i] = bv;
    for (int k = 0; k < K; k++) {
        float wv = w[k * N + n];
        #pragma unroll
        for (int i = 0; i < 4; i++) acc[i] += in[(m0 + i) * K + k] * wv;
    }
    #pragma unroll
    for (int i = 0; i < 4; i++) {
        float v = acc[i];
        out[(m0 + i) * N + n] = ACT ? tanhf(v) : v;
    }
}

// third encoder layer -> h-stack [x | h0], stride 520
__global__ void k_enc3(const float* __restrict__ h2, const float* __restrict__ w,
                       const float* __restrict__ bias, const float* __restrict__ x,
                       float* __restrict__ hstack) {
    int n  = blockIdx.x * 256 + threadIdx.x;   // 0..511
    int m0 = blockIdx.y * 4;
    float acc[4];
    float bv = bias[n];
    #pragma unroll
    for (int i = 0; i < 4; i++) acc[i] = bv;
    for (int k = 0; k < Ez; k++) {
        float wv = w[k * 512 + n];
        #pragma unroll
        for (int i = 0; i < 4; i++) acc[i] += h2[(m0 + i) * Ez + k] * wv;
    }
    #pragma unroll
    for (int i = 0; i < 4; i++) hstack[(m0 + i) * Hz + Sz + n] = acc[i];
    if (blockIdx.x == 0 && threadIdx.x < Sz) {
        #pragma unroll
        for (int i = 0; i < 4; i++)
            hstack[(m0 + i) * Hz + threadIdx.x] = x[(m0 + i) * Sz + threadIdx.x];
    }
}

// Persistent cooperative LSTM: 256 WGs (16 groups x 16 slices), 512 threads (8 waves).
// Tagged exchange + XCD swizzle (round-11 baseline). This round, two local fixes:
// (1) __launch_bounds__(512,1): lifts the 128-VGPR cap that was spilling bfrag[2][17]
//     (136 VGPRs) to scratch — grid is 1 WG/CU so 2-blocks/CU bought nothing.
// (2) Gate 4x4 shfl-transpose: the 4 gates of unit j sit in 4 adjacent lanes; a
//     butterfly transpose gives each lane (i,f,g,o) for one (unit,row). Cell update
//     runs in registers (c, h_prev per-lane persistent; static ownership), gates_lds
//     and c_lds deleted, one barrier deleted, and each wave publishes its tagged h
//     right after its own MFMA — shortening the inter-WG chain. One shfl re-swizzle
//     keeps stores coalesced. Per-dword tags make dword-granularity stores
//     protocol-neutral (consumer still loads qwords, checks both tags).
__global__ __launch_bounds__(NTHR, 1) void k_lstm(
        const ushort* __restrict__ wbt, const float* __restrict__ rnn_in,
        const float* __restrict__ deltas, const int* __restrict__ h_lens,
        const float* __restrict__ W_ih, const float* __restrict__ b_lstm,
        ull* h_global, const int* __restrict__ sortedidx,
        float* __restrict__ last) {
    __shared__ __align__(16) ushort a_lds[RG * KW];     // 16,640 B (packed bf16 A tile)
    __shared__ int   rowg[RG];
    __shared__ int   hl_s[RG];

    const int tid = threadIdx.x;
    const int bid = blockIdx.x;
    // XCD-locality swizzle: all bids of group g satisfy bid%8 == g&7 (bijective).
    const int g   = (bid & 7) | ((bid >> 7) << 3);
    const int s   = (bid >> 3) & 15;

    if (tid < RG) {
        int o = sortedidx[g * RG + tid];
        rowg[tid] = o;
        hl_s[tid] = h_lens[o];
    }
    __syncthreads();

    const int lane = tid & 63, wvi = tid >> 6;       // wvi 0..7
    const int l15 = lane & 15, quad = lane >> 4;
    const int ntile = (wvi == 0) ? 2 : 1;
    const int tiles[2] = { wvi, 8 };                  // wave 0 also covers tile 8

    int myrows[4];
    #pragma unroll
    for (int r = 0; r < 4; r++) myrows[r] = rowg[quad * 4 + r];
    const int gmax = hl_s[0];

    // post-transpose ownership: tile i -> (unit ju_i, row em_i), one per lane
    int ju_[2], jg_[2];
    #pragma unroll
    for (int i = 0; i < 2; i++) {
        ju_[i] = tiles[i] * 4 + (l15 >> 2);
        jg_[i] = s * JW + ju_[i];
    }
    const int em   = quad * 4 + (l15 & 3);           // elementwise row 0..15
    const int ehl  = hl_s[em];
    const int eorig = rowg[em];
    // store-swizzle source lane (swap 2-bit fields of l15)
    const int ssrc = (lane & 48) | ((l15 & 3) << 2) | (l15 >> 2);
    // store target (after swizzle): unit tiles[i]*4 + (l15&3), row quad*4 + (l15>>2)
    const int sm   = quad * 4 + (l15 >> 2);

    // ---- B fragments (W_hh slice) persistent in VGPRs: <=2 tiles x 17 x uint4 ----
    s16x8 bfrag[2][KIT];
    #pragma unroll
    for (int i = 0; i < 2; i++) {
        int nl = tiles[i] * 16 + l15;
        bool okrow = (i < ntile) && (nl < NW);
        const uint* wrow = (const uint*)wbt + (size_t)(s * NW + (nl < NW ? nl : 0)) * KD;
        #pragma unroll
        for (int kit = 0; kit < KIT; kit++) {
            s16x8 z = {0, 0, 0, 0, 0, 0, 0, 0};
            if (okrow && (kit * 32 + quad * 8 < KW))
                z = __builtin_bit_cast(s16x8, *(const uint4*)(wrow + kit * 16 + quad * 4));
            bfrag[i][kit] = z;
        }
    }

    // W_ih / bias columns for this lane's n positions
    float wihreg[2][CD1], breg[2];
    #pragma unroll
    for (int i = 0; i < 2; i++) {
        int nl = tiles[i] * 16 + l15;
        int jg = s * JW + (nl >> 2);
        bool ok = (i < ntile) && (nl < NW) && (jg < Hz);
        int col = (nl & 3) * Hz + (jg < Hz ? jg : 0);
        breg[i] = ok ? b_lstm[col] : 0.0f;
        #pragma unroll
        for (int q = 0; q < CD1; q++) wihreg[i][q] = ok ? W_ih[q * H4 + col] : 0.0f;
    }

    // per-lane persistent cell/hidden state for owned (unit,row)
    float c_reg[2] = {0.0f, 0.0f};
    float hprev[2] = {0.0f, 0.0f};

    // double-buffered tagged h state: buffer b at h_global + b*Bz*KD (qwords)
    ull* hbuf0 = h_global + (size_t)g * RG * KD;
    ull* hbuf1 = h_global + (size_t)Bz * KD + (size_t)g * RG * KD;

    // gather slot validity: it=0..7 always valid; it=8 only for tid<64
    const uint done_init = (tid < HGTQ - 8 * NTHR) ? 0u : 0x100u;

    for (int t = 0; t < gmax; t++) {
        ull* hwq = (t & 1) ? hbuf1 : hbuf0;          // write h(t)
        const ull* hrq = (t & 1) ? hbuf0 : hbuf1;    // read  h(t-1)  (t=0 -> buf1 = h0)
        uint* hwd = (uint*)hwq;                      // dword view for tagged stores

        // acc init = u_t @ W_ih + b — independent of h(t-1), issued before the gather
        float uu[4][CD1];
        #pragma unroll
        for (int r = 0; r < 4; r++) {
            const float* up = rnn_in + ((size_t)myrows[r] * Tz + t) * CD1;
            #pragma unroll
            for (int q = 0; q < CD1; q++) uu[r][q] = up[q];
        }
        f32x4 acc[2];
        #pragma unroll
        for (int i = 0; i < 2; i++) {
            #pragma unroll
            for (int r = 0; r < 4; r++) {
                float a0 = breg[i];
                #pragma unroll
                for (int q = 0; q < CD1; q++) a0 += uu[r][q] * wihreg[i][q];
                acc[i][r] = a0;
            }
        }

        // tagged gather (detect+gather merged): verify tag == t-1 per dword,
        // pack verified bf16 pairs into a_lds; retry only stale qwords.
        {
            const uint want = (uint)((t - 1) & 0xFFFF);
            uint done = done_init;
            for (;;) {
                ull v[9];
                #pragma unroll
                for (int it = 0; it < 9; it++) {
                    int q = tid + it * NTHR;
                    bool act = !((done >> it) & 1u);
                    v[it] = act ? __hip_atomic_load(hrq + q, __ATOMIC_RELAXED,
                                                    __HIP_MEMORY_SCOPE_AGENT)
                                : 0ull;
                }
                #pragma unroll
                for (int it = 0; it < 9; it++) {
                    if (!((done >> it) & 1u)) {
                        int q = tid + it * NTHR;
                        uint lo = (uint)v[it], hi = (uint)(v[it] >> 32);
                        if ((lo >> 16) == want && (hi >> 16) == want) {
                            ((uint*)a_lds)[q] = (lo & 0xFFFFu) | (hi << 16);
                            done |= 1u << it;
                        }
                    }
                }
                if (__syncthreads_and((int)(done == 0x1FFu))) break;
                __builtin_amdgcn_s_sleep(4);
            }
        }

        // t=0: initialize per-lane h_prev from the gathered h0 tile
        if (t == 0) {
            #pragma unroll
            for (int i = 0; i < 2; i++) {
                if (i >= ntile) break;
                if (ju_[i] < JW && jg_[i] < Hz) {
                    uint pd = ((const uint*)a_lds)[em * KD + (jg_[i] >> 1)];
                    hprev[i] = bf2f((ushort)((jg_[i] & 1) ? (pd >> 16) : (pd & 0xFFFFu)));
                }
            }
        }

        // MFMA k-loop: A from LDS (packed), B from registers
        for (int kit = 0; kit < KIT; kit++) {
            int kq = kit * 32 + quad * 8;
            s16x8 af = {0, 0, 0, 0, 0, 0, 0, 0};
            if (kq < KW)
                af = __builtin_bit_cast(s16x8,
                    *(const uint4*)((const uint*)a_lds + l15 * KD + kit * 16 + quad * 4));
            #pragma unroll
            for (int i = 0; i < 2; i++) {
                if (i >= ntile) break;
                acc[i] = __builtin_amdgcn_mfma_f32_16x16x32_bf16(af, bfrag[i][kit], acc[i], 0, 0, 0);
            }
        }

        // per-tile: 4x4 gate transpose -> in-register cell update -> tagged store
        const uint tagw = ((uint)t & 0xFFFFu) << 16;
        #pragma unroll
        for (int i = 0; i < 2; i++) {
            if (i >= ntile) break;
            float v0 = acc[i][0], v1 = acc[i][1], v2 = acc[i][2], v3 = acc[i][3];
            float x;
            // butterfly 4x4 transpose across 4-lane groups
            x = __shfl_xor((lane & 1) ? v0 : v1, 1);
            if (lane & 1) v0 = x; else v1 = x;
            x = __shfl_xor((lane & 1) ? v2 : v3, 1);
            if (lane & 1) v2 = x; else v3 = x;
            x = __shfl_xor((lane & 2) ? v0 : v2, 2);
            if (lane & 2) v0 = x; else v2 = x;
            x = __shfl_xor((lane & 2) ? v1 : v3, 2);
            if (lane & 2) v1 = x; else v3 = x;
            // lane now holds (i,f,g,o) for (unit ju_[i], row em)
            uint tg = 0u;
            bool valid = (ju_[i] < JW) && (jg_[i] < Hz);
            if (valid) {
                float hnew;
                if (t < ehl) {
                    float ig = sigf(v0), fg = sigf(v1), gt = tanhf(v2), og = sigf(v3);
                    float cn = fg * c_reg[i] + ig * gt;
                    c_reg[i] = cn;
                    float hn = og * tanhf(cn);
                    if (t == ehl - 1) {
                        float d = deltas[(size_t)eorig * Tz + t];
                        last[(size_t)eorig * Hz + jg_[i]] = (1.0f - d) * hprev[i] + d * hn;
                    }
                    hnew = hn;
                } else {
                    hnew = hprev[i];
                }
                ushort hb = f2bf(hnew);
                hprev[i] = bf2f(hb);
                tg = tagw | (uint)hb;
            }
            // re-swizzle for coalesced store: lane stores (unit tiles[i]*4+(l15&3), row sm)
            uint tgs = __shfl(tg, ssrc);
            int ju_s = tiles[i] * 4 + (l15 & 3);
            int jg_s = s * JW + ju_s;
            if (ju_s < JW && jg_s < Hz) {
                __hip_atomic_store(hwd + sm * KW + jg_s, tgs,
                                   __ATOMIC_RELAXED, __HIP_MEMORY_SCOPE_AGENT);
            }
        }

        // step-end barrier: a_lds WAR (all waves read full a_lds in MFMA) before
        // next step's gather overwrites it. Stores need no ordering — tags self-verify.
        __syncthreads();
    }
}

// final projection: (256,1040) @ (1040,8) + bias, one block per row
__global__ void k_dec3(const float* __restrict__ z2, const float* __restrict__ w,
                       const float* __restrict__ bias, float* __restrict__ out) {
    int m = blockIdx.x, tid = threadIdx.x;
    float p[8];
    #pragma unroll
    for (int n = 0; n < 8; n++) p[n] = 0.0f;
    for (int k = tid; k < Dz; k += 256) {
        float zv = z2[(size_t)m * Dz + k];
        #pragma unroll
        for (int n = 0; n < 8; n++) p[n] += zv * w[k * 8 + n];
    }
    __shared__ float red[256][8];
    #pragma unroll
    for (int n = 0; n < 8; n++) red[tid][n] = p[n];
    __syncthreads();
    for (int s2 = 128; s2 > 0; s2 >>= 1) {
        if (tid < s2) {
            #pragma unroll
            for (int n = 0; n < 8; n++) red[tid][n] += red[tid + s2][n];
        }
        __syncthreads();
    }
    if (tid < 8) out[m * 8 + tid] = red[0][tid] + bias[tid];
}

extern "C" void kernel_launch(void* const* d_in, const int* in_sizes, int n_in,
                              void* d_out, int out_size, void* d_ws, size_t ws_size,
                              hipStream_t stream) {
    const float* x       = (const float*)d_in[0];
    const float* rnn_inp = (const float*)d_in[1];
    const float* deltas  = (const float*)d_in[2];
    const int*   h_lens  = (const int*)  d_in[3];
    const float* enc_w1  = (const float*)d_in[4];
    const float* enc_b1  = (const float*)d_in[5];
    const float* enc_w2  = (const float*)d_in[6];
    const float* enc_b2  = (const float*)d_in[7];
    const float* enc_w3  = (const float*)d_in[8];
    const float* enc_b3  = (const float*)d_in[9];
    const float* W_ih    = (const float*)d_in[10];
    const float* W_hh    = (const float*)d_in[11];
    const float* b_lstm  = (const float*)d_in[12];
    const float* dec_w1  = (const float*)d_in[13];
    const float* dec_b1  = (const float*)d_in[14];
    const float* dec_w2  = (const float*)d_in[15];
    const float* dec_b2  = (const float*)d_in[16];
    const float* dec_w3  = (const float*)d_in[17];
    const float* dec_b3  = (const float*)d_in[18];
    (void)in_sizes; (void)n_in; (void)out_size; (void)ws_size;

    char* base = (char*)d_ws;
    size_t off = 0;
    auto alloc = [&](size_t bytes) { void* p = base + off; off = (off + bytes + 255) & ~(size_t)255; return p; };
    ushort* wbt      = (ushort*)alloc((size_t)NW * NSL * KW * 2);   // 2,263,040
    ull*    h_glob   = (ull*)   alloc((size_t)2 * Bz * KD * 8);     // 1,064,960 (tagged, 2 buffers)
    float*  hA       = (float*) alloc((size_t)Bz * KW * 4);
    float*  h1       = (float*) alloc((size_t)Bz * Ez * 4);
    float*  h2       = (float*) alloc((size_t)Bz * Ez * 4);
    float*  lastb    = (float*) alloc((size_t)Bz * Hz * 4);
    float*  z1       = (float*) alloc((size_t)Bz * Dz * 4);
    float*  z2       = (float*) alloc((size_t)Bz * Dz * 4);
    int*    sortedix = (int*)   alloc(Bz * 4);
    float*  outp = (float*)d_out;

    k_sort<<<1, 256, 0, stream>>>(h_lens, sortedix);
    {
        int total = NW * NSL * KW;
        k_prep_w<<<(total + 255) / 256, 256, 0, stream>>>(W_hh, wbt);
    }

    k_mlp<Sz, Ez, 1><<<dim3(4, 64), 256, 0, stream>>>(x,  enc_w1, enc_b1, h1);
    k_mlp<Ez, Ez, 1><<<dim3(4, 64), 256, 0, stream>>>(h1, enc_w2, enc_b2, h2);
    k_enc3<<<dim3(2, 64), 256, 0, stream>>>(h2, enc_w3, enc_b3, x, hA);
    {
        int total = Bz * KD;
        // seed buffer 1 (read at t=0) with tag 0xFFFF
        k_hinit<<<(total + 255) / 256, 256, 0, stream>>>(hA, sortedix,
                                                         h_glob + (size_t)Bz * KD);
    }

    {
        void* args[] = { (void*)&wbt, (void*)&rnn_inp, (void*)&deltas, (void*)&h_lens,
                         (void*)&W_ih, (void*)&b_lstm, (void*)&h_glob, (void*)&sortedix,
                         (void*)&lastb };
        hipLaunchCooperativeKernel(reinterpret_cast<void*>(k_lstm), dim3(NG * NSL), dim3(NTHR),
                                   args, 0, stream);
    }

    k_mlp<Hz, Dz, 1><<<dim3(5, 64), 256, 0, stream>>>(lastb, dec_w1, dec_b1, z1);
    k_mlp<Dz, Dz, 1><<<dim3(5, 64), 256, 0, stream>>>(z1,   dec_w2, dec_b2, z2);
    k_dec3<<<Bz, 256, 0, stream>>>(z2, dec_w3, dec_b3, outp);
}

// Round 13
// 2148.100 us; speedup vs baseline: 1.8741x; 1.8741x over previous
//
#include <hip/hip_runtime.h>
#include <math.h>

#define Bz   256
#define Tz   512
#define Sz   8
#define CD1  5
#define Hz   520
#define H4   2080
#define Ez   1024
#define Dz   1040

// persistent LSTM geometry
#define NG   16     // row groups
#define NSL  16     // j-slices per group (NG*NSL = 256 WGs, 1 per CU)
#define RG   16     // rows per group
#define JW   34     // j per slice (16*34 = 544 >= 520)
#define NW   136    // gate columns per slice (JW*4)
#define KW   520    // K extent
#define KD   260    // packed dwords (= tagged qwords) per row
#define KIT  17     // k-iterations of 32 (ceil(520/32))
#define HGTQ 4160   // tagged qwords per group (RG*KD)
#define NTHR 512    // threads per WG (8 waves)

typedef float f32x4 __attribute__((ext_vector_type(4)));
typedef short s16x8 __attribute__((ext_vector_type(8)));
typedef unsigned long long ull;

__device__ __forceinline__ ushort f2bf(float f) {
    uint u = __float_as_uint(f);
    uint r = (u + 0x7fffu + ((u >> 16) & 1u)) >> 16;
    return (ushort)r;
}
__device__ __forceinline__ float bf2f(ushort h) { return __uint_as_float(((uint)h) << 16); }
__device__ __forceinline__ float sigf(float v) { return 1.0f / (1.0f + expf(-v)); }

// rank-sort rows by h_len descending (ties by index) — O(n^2), one block
__global__ void k_sort(const int* __restrict__ hl, int* __restrict__ sortedidx) {
    __shared__ int s[Bz];
    int i = threadIdx.x;
    s[i] = hl[i];
    __syncthreads();
    int mine = s[i], rank = 0;
    for (int j = 0; j < Bz; j++) {
        int o = s[j];
        rank += (o > mine) || (o == mine && j < i);
    }
    sortedidx[rank] = i;
}

// W_hh -> bf16, layout wbt[n][k], n_global = s*NW + nl; j = n_global>>2, gate = n&3
__global__ void k_prep_w(const float* __restrict__ whh, ushort* __restrict__ wbt) {
    int idx = blockIdx.x * 256 + threadIdx.x;
    if (idx >= NW * NSL * KW) return;
    int n = idx / KW, k = idx - n * KW;
    int j = n >> 2, gate = n & 3;
    float v = (j < Hz) ? whh[(size_t)k * H4 + gate * Hz + j] : 0.0f;
    wbt[idx] = f2bf(v);
}

// permute h0_stack rows into sorted order, TAGGED (tag=0xFFFF) qwords, into buffer 1
__global__ void k_hinit(const float* __restrict__ hA, const int* __restrict__ sortedidx,
                        ull* __restrict__ h_buf1) {
    int idx = blockIdx.x * 256 + threadIdx.x;
    if (idx >= Bz * KD) return;
    int rank = idx / KD, kd = idx - rank * KD;
    const float* src = hA + (size_t)sortedidx[rank] * KW + 2 * kd;
    uint lo = 0xFFFF0000u | (uint)f2bf(src[0]);
    uint hi = 0xFFFF0000u | (uint)f2bf(src[1]);
    h_buf1[idx] = (ull)lo | ((ull)hi << 32);
}

// out[m][n] = act( in[m][:] @ w[:][n] + bias[n] ), 4 rows/block, 256 threads over n
template<int K, int N, int ACT>
__global__ void k_mlp(const float* __restrict__ in, const float* __restrict__ w,
                      const float* __restrict__ bias, float* __restrict__ out) {
    int n  = blockIdx.x * 256 + threadIdx.x;
    int m0 = blockIdx.y * 4;
    if (n >= N) return;
    float acc[4];
    float bv = bias[n];
    #pragma unroll
    for (int i = 0; i < 4; i++) acc[i] = bv;
    for (int k = 0; k < K; k++) {
        float wv = w[k * N + n];
        #pragma unroll
        for (int i = 0; i < 4; i++) acc[i] += in[(m0 + i) * K + k] * wv;
    }
    #pragma unroll
    for (int i = 0; i < 4; i++) {
        float v = acc[i];
        out[(m0 + i) * N + n] = ACT ? tanhf(v) : v;
    }
}

// third encoder layer -> h-stack [x | h0], stride 520
__global__ void k_enc3(const float* __restrict__ h2, const float* __restrict__ w,
                       const float* __restrict__ bias, const float* __restrict__ x,
                       float* __restrict__ hstack) {
    int n  = blockIdx.x * 256 + threadIdx.x;   // 0..511
    int m0 = blockIdx.y * 4;
    float acc[4];
    float bv = bias[n];
    #pragma unroll
    for (int i = 0; i < 4; i++) acc[i] = bv;
    for (int k = 0; k < Ez; k++) {
        float wv = w[k * 512 + n];
        #pragma unroll
        for (int i = 0; i < 4; i++) acc[i] += h2[(m0 + i) * Ez + k] * wv;
    }
    #pragma unroll
    for (int i = 0; i < 4; i++) hstack[(m0 + i) * Hz + Sz + n] = acc[i];
    if (blockIdx.x == 0 && threadIdx.x < Sz) {
        #pragma unroll
        for (int i = 0; i < 4; i++)
            hstack[(m0 + i) * Hz + threadIdx.x] = x[(m0 + i) * Sz + threadIdx.x];
    }
}

// Persistent cooperative LSTM: 256 WGs (16 groups x 16 slices), 512 threads (8 waves).
// Round-11 baseline (tagged exchange + XCD swizzle, measured 2584us total) with ONE
// change: the tagged-gather retry loop is DE-QUANTIZED — no per-iteration
// __syncthreads_and rendezvous, no 256cy sleep. Each thread independently re-samples
// only its stale qwords (bounded volume: after pass 1 the stale set is the slowest
// producer's slice) with s_sleep(1) spacing, then parks at ONE final barrier.
// Round-12's dword/shfl store path is fully reverted (qword tid-consecutive stores;
// WRITE_SIZE amplification was its failure mode).
__global__ __launch_bounds__(NTHR, 2) void k_lstm(
        const ushort* __restrict__ wbt, const float* __restrict__ rnn_in,
        const float* __restrict__ deltas, const int* __restrict__ h_lens,
        const float* __restrict__ W_ih, const float* __restrict__ b_lstm,
        ull* h_global, const int* __restrict__ sortedidx,
        float* __restrict__ last) {
    __shared__ __align__(16) ushort a_lds[RG * KW];     // 16,640 B (packed bf16 A tile)
    __shared__ __align__(16) float  gates_lds[RG * NW]; //  8,704 B (fp32 gate pre-acts)
    __shared__ float c_lds[RG * JW];                    //  2,176 B
    __shared__ int   rowg[RG];
    __shared__ int   hl_s[RG];

    const int tid = threadIdx.x;
    const int bid = blockIdx.x;
    // XCD-locality swizzle: all bids of group g satisfy bid%8 == g&7 (bijective).
    const int g   = (bid & 7) | ((bid >> 7) << 3);
    const int s   = (bid >> 3) & 15;

    if (tid < RG) {
        int o = sortedidx[g * RG + tid];
        rowg[tid] = o;
        hl_s[tid] = h_lens[o];
    }
    for (int idx = tid; idx < RG * JW; idx += NTHR) c_lds[idx] = 0.0f;
    __syncthreads();

    const int lane = tid & 63, wvi = tid >> 6;       // wvi 0..7
    const int l15 = lane & 15, quad = lane >> 4;
    const int ntile = (wvi == 0) ? 2 : 1;
    const int tiles[2] = { wvi, 8 };                  // wave 0 also covers tile 8

    int myrows[4];
    #pragma unroll
    for (int r = 0; r < 4; r++) myrows[r] = rowg[quad * 4 + r];
    const int gmax = hl_s[0];

    // ---- B fragments (W_hh slice) persistent in VGPRs: <=2 tiles x 17 x uint4 ----
    s16x8 bfrag[2][KIT];
    #pragma unroll
    for (int i = 0; i < 2; i++) {
        int nl = tiles[i] * 16 + l15;
        bool okrow = (i < ntile) && (nl < NW);
        const uint* wrow = (const uint*)wbt + (size_t)(s * NW + (nl < NW ? nl : 0)) * KD;
        #pragma unroll
        for (int kit = 0; kit < KIT; kit++) {
            s16x8 z = {0, 0, 0, 0, 0, 0, 0, 0};
            if (okrow && (kit * 32 + quad * 8 < KW))
                z = __builtin_bit_cast(s16x8, *(const uint4*)(wrow + kit * 16 + quad * 4));
            bfrag[i][kit] = z;
        }
    }

    // W_ih / bias columns for this lane's n positions
    float wihreg[2][CD1], breg[2];
    #pragma unroll
    for (int i = 0; i < 2; i++) {
        int nl = tiles[i] * 16 + l15;
        int jg = s * JW + (nl >> 2);
        bool ok = (i < ntile) && (nl < NW) && (jg < Hz);
        int col = (nl & 3) * Hz + (jg < Hz ? jg : 0);
        breg[i] = ok ? b_lstm[col] : 0.0f;
        #pragma unroll
        for (int q = 0; q < CD1; q++) wihreg[i][q] = ok ? W_ih[q * H4 + col] : 0.0f;
    }

    // double-buffered tagged h state: buffer b at h_global + b*Bz*KD (qwords)
    ull* hbuf0 = h_global + (size_t)g * RG * KD;
    ull* hbuf1 = h_global + (size_t)Bz * KD + (size_t)g * RG * KD;

    // gather slot validity: it=0..7 always valid; it=8 only for tid<64
    const uint done_init = (tid < HGTQ - 8 * NTHR) ? 0u : 0x100u;

    for (int t = 0; t < gmax; t++) {
        ull* hwq = (t & 1) ? hbuf1 : hbuf0;          // write h(t)
        const ull* hrq = (t & 1) ? hbuf0 : hbuf1;    // read  h(t-1)  (t=0 -> buf1 = h0)

        // acc init = u_t @ W_ih + b — independent of h(t-1), issued before the gather
        float uu[4][CD1];
        #pragma unroll
        for (int r = 0; r < 4; r++) {
            const float* up = rnn_in + ((size_t)myrows[r] * Tz + t) * CD1;
            #pragma unroll
            for (int q = 0; q < CD1; q++) uu[r][q] = up[q];
        }
        f32x4 acc[2];
        #pragma unroll
        for (int i = 0; i < 2; i++) {
            #pragma unroll
            for (int r = 0; r < 4; r++) {
                float a0 = breg[i];
                #pragma unroll
                for (int q = 0; q < CD1; q++) a0 += uu[r][q] * wihreg[i][q];
                acc[i][r] = a0;
            }
        }

        // tagged gather (detect+gather merged), DE-QUANTIZED: each thread re-samples
        // only its stale qwords until all 9 verify, then parks at ONE final barrier.
        {
            const uint want = (uint)((t - 1) & 0xFFFF);
            uint done = done_init;
            while (done != 0x1FFu) {
                ull v[9];
                #pragma unroll
                for (int it = 0; it < 9; it++) {
                    int q = tid + it * NTHR;
                    bool act = !((done >> it) & 1u);
                    v[it] = act ? __hip_atomic_load(hrq + q, __ATOMIC_RELAXED,
                                                    __HIP_MEMORY_SCOPE_AGENT)
                                : 0ull;
                }
                #pragma unroll
                for (int it = 0; it < 9; it++) {
                    if (!((done >> it) & 1u)) {
                        int q = tid + it * NTHR;
                        uint lo = (uint)v[it], hi = (uint)(v[it] >> 32);
                        if ((lo >> 16) == want && (hi >> 16) == want) {
                            ((uint*)a_lds)[q] = (lo & 0xFFFFu) | (hi << 16);
                            done |= 1u << it;
                        }
                    }
                }
                if (done != 0x1FFu) __builtin_amdgcn_s_sleep(1);
            }
            __syncthreads();
        }

        // MFMA k-loop: A from LDS (packed), B from registers
        for (int kit = 0; kit < KIT; kit++) {
            int kq = kit * 32 + quad * 8;
            s16x8 af = {0, 0, 0, 0, 0, 0, 0, 0};
            if (kq < KW)
                af = __builtin_bit_cast(s16x8,
                    *(const uint4*)((const uint*)a_lds + l15 * KD + kit * 16 + quad * 4));
            #pragma unroll
            for (int i = 0; i < 2; i++) {
                if (i >= ntile) break;
                acc[i] = __builtin_amdgcn_mfma_f32_16x16x32_bf16(af, bfrag[i][kit], acc[i], 0, 0, 0);
            }
        }

        // gates (pre-activation) -> dedicated LDS region
        #pragma unroll
        for (int i = 0; i < 2; i++) {
            if (i >= ntile) break;
            int nl = tiles[i] * 16 + l15;
            if (nl < NW) {
                #pragma unroll
                for (int r = 0; r < 4; r++) gates_lds[(quad * 4 + r) * NW + nl] = acc[i][r];
            }
        }
        __syncthreads();

        // paired elementwise cell update; tagged 8B h stores (tag = t).
        // Frozen rows (t >= hl) re-store their unchanged value (from a_lds) with
        // the fresh tag so peers' tag-checks always complete.
        if (tid < RG * (JW / 2)) {
            int m  = tid / (JW / 2), jp = tid - m * (JW / 2);
            int jj = 2 * jp;
            int jglob = s * JW + jj;                 // even
            if (jglob < Hz) {
                uint pd = ((const uint*)a_lds)[m * KD + (jglob >> 1)];  // h(t-1) packed
                ushort h0b, h1b;
                if (t < hl_s[m]) {
                    float2 c2 = *(float2*)&c_lds[m * JW + jj];
                    const float* gp = &gates_lds[m * NW + jj * 4];
                    float4 gA = *(const float4*)gp;
                    float4 gB = *(const float4*)(gp + 4);
                    float i0 = sigf(gA.x), f0 = sigf(gA.y), g0 = tanhf(gA.z), o0 = sigf(gA.w);
                    float i1 = sigf(gB.x), f1 = sigf(gB.y), g1 = tanhf(gB.z), o1 = sigf(gB.w);
                    float cn0 = f0 * c2.x + i0 * g0;
                    float cn1 = f1 * c2.y + i1 * g1;
                    float hn0 = o0 * tanhf(cn0);
                    float hn1 = o1 * tanhf(cn1);
                    c2.x = cn0; c2.y = cn1;
                    *(float2*)&c_lds[m * JW + jj] = c2;
                    if (t == hl_s[m] - 1) {
                        float hp0 = bf2f((ushort)(pd & 0xFFFFu));
                        float hp1 = bf2f((ushort)(pd >> 16));
                        int orig = rowg[m];
                        float d = deltas[(size_t)orig * Tz + t];
                        last[(size_t)orig * Hz + jglob]     = (1.0f - d) * hp0 + d * hn0;
                        last[(size_t)orig * Hz + jglob + 1] = (1.0f - d) * hp1 + d * hn1;
                    }
                    h0b = f2bf(hn0);
                    h1b = f2bf(hn1);
                } else {
                    h0b = (ushort)(pd & 0xFFFFu);    // frozen value, re-tag only
                    h1b = (ushort)(pd >> 16);
                }
                uint tagw = ((uint)t & 0xFFFFu) << 16;
                ull pk = (ull)(tagw | (uint)h0b) | ((ull)(tagw | (uint)h1b) << 32);
                __hip_atomic_store(hwq + m * KD + (jglob >> 1), pk,
                                   __ATOMIC_RELAXED, __HIP_MEMORY_SCOPE_AGENT);
            }
        }

        // step-end barrier: protects a_lds/gates WAR for next iteration and
        // (via its vmcnt drain) pushes this step's tagged stores toward L2/L3.
        __syncthreads();
    }
}

// final projection: (256,1040) @ (1040,8) + bias, one block per row
__global__ void k_dec3(const float* __restrict__ z2, const float* __restrict__ w,
                       const float* __restrict__ bias, float* __restrict__ out) {
    int m = blockIdx.x, tid = threadIdx.x;
    float p[8];
    #pragma unroll
    for (int n = 0; n < 8; n++) p[n] = 0.0f;
    for (int k = tid; k < Dz; k += 256) {
        float zv = z2[(size_t)m * Dz + k];
        #pragma unroll
        for (int n = 0; n < 8; n++) p[n] += zv * w[k * 8 + n];
    }
    __shared__ float red[256][8];
    #pragma unroll
    for (int n = 0; n < 8; n++) red[tid][n] = p[n];
    __syncthreads();
    for (int s2 = 128; s2 > 0; s2 >>= 1) {
        if (tid < s2) {
            #pragma unroll
            for (int n = 0; n < 8; n++) red[tid][n] += red[tid + s2][n];
        }
        __syncthreads();
    }
    if (tid < 8) out[m * 8 + tid] = red[0][tid] + bias[tid];
}

extern "C" void kernel_launch(void* const* d_in, const int* in_sizes, int n_in,
                              void* d_out, int out_size, void* d_ws, size_t ws_size,
                              hipStream_t stream) {
    const float* x       = (const float*)d_in[0];
    const float* rnn_inp = (const float*)d_in[1];
    const float* deltas  = (const float*)d_in[2];
    const int*   h_lens  = (const int*)  d_in[3];
    const float* enc_w1  = (const float*)d_in[4];
    const float* enc_b1  = (const float*)d_in[5];
    const float* enc_w2  = (const float*)d_in[6];
    const float* enc_b2  = (const float*)d_in[7];
    const float* enc_w3  = (const float*)d_in[8];
    const float* enc_b3  = (const float*)d_in[9];
    const float* W_ih    = (const float*)d_in[10];
    const float* W_hh    = (const float*)d_in[11];
    const float* b_lstm  = (const float*)d_in[12];
    const float* dec_w1  = (const float*)d_in[13];
    const float* dec_b1  = (const float*)d_in[14];
    const float* dec_w2  = (const float*)d_in[15];
    const float* dec_b2  = (const float*)d_in[16];
    const float* dec_w3  = (const float*)d_in[17];
    const float* dec_b3  = (const float*)d_in[18];
    (void)in_sizes; (void)n_in; (void)out_size; (void)ws_size;

    char* base = (char*)d_ws;
    size_t off = 0;
    auto alloc = [&](size_t bytes) { void* p = base + off; off = (off + bytes + 255) & ~(size_t)255; return p; };
    ushort* wbt      = (ushort*)alloc((size_t)NW * NSL * KW * 2);   // 2,263,040
    ull*    h_glob   = (ull*)   alloc((size_t)2 * Bz * KD * 8);     // 1,064,960 (tagged, 2 buffers)
    float*  hA       = (float*) alloc((size_t)Bz * KW * 4);
    float*  h1       = (float*) alloc((size_t)Bz * Ez * 4);
    float*  h2       = (float*) alloc((size_t)Bz * Ez * 4);
    float*  lastb    = (float*) alloc((size_t)Bz * Hz * 4);
    float*  z1       = (float*) alloc((size_t)Bz * Dz * 4);
    float*  z2       = (float*) alloc((size_t)Bz * Dz * 4);
    int*    sortedix = (int*)   alloc(Bz * 4);
    float*  outp = (float*)d_out;

    k_sort<<<1, 256, 0, stream>>>(h_lens, sortedix);
    {
        int total = NW * NSL * KW;
        k_prep_w<<<(total + 255) / 256, 256, 0, stream>>>(W_hh, wbt);
    }

    k_mlp<Sz, Ez, 1><<<dim3(4, 64), 256, 0, stream>>>(x,  enc_w1, enc_b1, h1);
    k_mlp<Ez, Ez, 1><<<dim3(4, 64), 256, 0, stream>>>(h1, enc_w2, enc_b2, h2);
    k_enc3<<<dim3(2, 64), 256, 0, stream>>>(h2, enc_w3, enc_b3, x, hA);
    {
        int total = Bz * KD;
        // seed buffer 1 (read at t=0) with tag 0xFFFF
        k_hinit<<<(total + 255) / 256, 256, 0, stream>>>(hA, sortedix,
                                                         h_glob + (size_t)Bz * KD);
    }

    {
        void* args[] = { (void*)&wbt, (void*)&rnn_inp, (void*)&deltas, (void*)&h_lens,
                         (void*)&W_ih, (void*)&b_lstm, (void*)&h_glob, (void*)&sortedix,
                         (void*)&lastb };
        hipLaunchCooperativeKernel(reinterpret_cast<void*>(k_lstm), dim3(NG * NSL), dim3(NTHR),
                                   args, 0, stream);
    }

    k_mlp<Hz, Dz, 1><<<dim3(5, 64), 256, 0, stream>>>(lastb, dec_w1, dec_b1, z1);
    k_mlp<Dz, Dz, 1><<<dim3(5, 64), 256, 0, stream>>>(z1,   dec_w2, dec_b2, z2);
    k_dec3<<<Bz, 256, 0, stream>>>(z2, dec_w3, dec_b3, outp);
}